// Round 9
// baseline (270.656 us; speedup 1.0000x reference)
//
#include <hip/hip_runtime.h>
#include <cstdint>

// ---------------------------------------------------------------------------
// ATSS post-processor v6: cheap full pass (logit prefilter -> block-aggregated
// list) -> fine-hist exact threshold -> barrier-free rank-sort + decode ->
// parallel mask-NMS -> single-wave serial scan. Guarded exact fallback.
//
static constexpr int NI=8, CC=80, LL=25600, PRE_K=1000, POST_K=100;
static constexpr int HSIZE=2048;
static constexpr int CPCH=8, NCH=10, LPB=1024, LBLK=25, BPI=NCH*LBLK;  // 250 blk/img
static constexpr int BUFC=768;        // per-block LDS candidate buffer
static constexpr int CAPS=49152;      // static list cap/image (~29k expected)
static constexpr int CAPFB=8192;      // fallback list cap/image
static constexpr int CAP2=8192;       // rank-sort set cap/image
static constexpr float NMS_T=0.6f, BSTAT=0.65f, XPRE=0.619f;  // XPRE < logit(BSTAT)
static constexpr uint32_t FBASE=0x3F000000u;   // bits of 0.5f
static constexpr float CLIPV=4.135166556742356f, IMGM1=1279.0f;
typedef unsigned long long u64;

__device__ __forceinline__ float sigm(float x){ return 1.0f/(1.0f+expf(-x)); }

// ---------------------------------------------------------------------------
// K1: cheap full pass. 73% of elements: load+compare only. Survivors of the
// logit prefilter compute score; >= BSTAT appended to LDS buffer; ONE global
// atomic per block reserves candS space.
__global__ __launch_bounds__(256) void k_scan(const float* __restrict__ cls,
                                              const float* __restrict__ ctr,
                                              uint32_t* __restrict__ cntS,
                                              uint32_t* __restrict__ ovf,
                                              u64* __restrict__ candS) {
    __shared__ u64 sbuf[BUFC];
    __shared__ uint32_t s_cnt, s_base;
    const int t = threadIdx.x;
    if (t == 0) s_cnt = 0;
    __syncthreads();
    const int blk = blockIdx.x;
    const int n = blk / BPI, rem = blk % BPI, ch = rem / LBLK, lb = rem % LBLK;
    const int l0 = lb * LPB + t * 4;
    const uint32_t bstat = __float_as_uint(BSTAT);
    const float4 cr = *(const float4*)&ctr[(size_t)n * LL + l0];
    const float cv[4] = { sigm(cr.x), sigm(cr.y), sigm(cr.z), sigm(cr.w) };
    const float* base = cls + ((size_t)n * CC + ch * CPCH) * LL + l0;
    // 8 independent loads in flight
    const float4 x0 = *(const float4*)&base[(size_t)0 * LL];
    const float4 x1 = *(const float4*)&base[(size_t)1 * LL];
    const float4 x2 = *(const float4*)&base[(size_t)2 * LL];
    const float4 x3 = *(const float4*)&base[(size_t)3 * LL];
    const float4 x4 = *(const float4*)&base[(size_t)4 * LL];
    const float4 x5 = *(const float4*)&base[(size_t)5 * LL];
    const float4 x6 = *(const float4*)&base[(size_t)6 * LL];
    const float4 x7 = *(const float4*)&base[(size_t)7 * LL];
    const float4 xs[8] = { x0, x1, x2, x3, x4, x5, x6, x7 };
#pragma unroll
    for (int u = 0; u < CPCH; ++u) {
        const float xv[4] = { xs[u].x, xs[u].y, xs[u].z, xs[u].w };
#pragma unroll
        for (int k = 0; k < 4; ++k) {
            if (xv[k] > XPRE) {                    // rare survivor
                const uint32_t bits = __float_as_uint(sigm(xv[k]) * cv[k]);
                if (bits >= bstat) {
                    uint32_t pos = atomicAdd(&s_cnt, 1u);
                    if (pos < (uint32_t)BUFC) {
                        uint32_t idx = (uint32_t)(l0 + k) * CC + (uint32_t)(ch * CPCH + u);
                        sbuf[pos] = ((u64)bits << 32) | (uint32_t)(~idx);
                    }
                }
            }
        }
    }
    __syncthreads();
    if (t == 0) {
        s_base = atomicAdd(&cntS[n], s_cnt);
        if (s_cnt > (uint32_t)BUFC || s_base + s_cnt > (uint32_t)CAPS)
            atomicOr(&ovf[n], 1u);
    }
    __syncthreads();
    const uint32_t wr = min(s_cnt, (uint32_t)BUFC);
    const uint32_t b = s_base;
    if (b < (uint32_t)CAPS) {
        const uint32_t w = min(wr, (uint32_t)CAPS - b);
        for (uint32_t i = t; i < w; i += 256)
            candS[(size_t)n * CAPS + b + i] = sbuf[i];
    }
}

// ---------------------------------------------------------------------------
// K2: per image fine histogram (width 2^12 bits-units) over the compact list
// + exact top-1000 threshold + fast-path validity flag (merged).
__global__ __launch_bounds__(256) void k_thresh(const u64* __restrict__ candS,
                                                const uint32_t* __restrict__ cntS,
                                                const uint32_t* __restrict__ ovf,
                                                uint32_t* __restrict__ thr2,
                                                uint32_t* __restrict__ listlen,
                                                uint32_t* __restrict__ flag) {
    __shared__ uint32_t h[HSIZE];
    __shared__ uint32_t chunk[256];
    const int n = blockIdx.x, t = threadIdx.x;
    for (int i = t; i < HSIZE; i += 256) h[i] = 0u;
    __syncthreads();
    const uint32_t cnt = min(cntS[n], (uint32_t)CAPS);
    for (uint32_t i = t; i < cnt; i += 256) {
        const uint32_t bits = (uint32_t)(candS[(size_t)n * CAPS + i] >> 32);
        atomicAdd(&h[min(2047u, (bits - FBASE) >> 12)], 1u);
    }
    __syncthreads();
    uint32_t s = 0;
    for (int k = 0; k < 8; ++k) s += h[t * 8 + k];
    chunk[t] = s;
    __syncthreads();
    if (t == 0) {
        uint32_t cum = 0, nsel = 0;
        int T2 = -1;
        for (int c = 255; c >= 0 && T2 < 0; --c) {
            if (cum + chunk[c] >= (uint32_t)PRE_K) {
                for (int b = c * 8 + 7; b >= c * 8; --b) {
                    cum += h[b];
                    if (cum >= (uint32_t)PRE_K) { T2 = b; nsel = cum; break; }
                }
            } else cum += chunk[c];
        }
        const uint32_t tb = FBASE + ((uint32_t)max(T2, 0) << 12);
        thr2[n] = tb;
        listlen[n] = cnt;
        flag[n] = (T2 >= 0 && tb >= __float_as_uint(BSTAT) && !ovf[n] &&
                   nsel <= (uint32_t)CAP2) ? 1u : 0u;
    }
}

// ---------------------------------------------------------------------------
// Guarded fallback trio (normally early-exit): exact full rescan.
__global__ __launch_bounds__(256) void k_fbhist(const float* __restrict__ cls,
                                                const float* __restrict__ ctr,
                                                const uint32_t* __restrict__ flag,
                                                uint32_t* __restrict__ ghistC) {
    const int blk = blockIdx.x;
    const int n = blk / BPI;
    if (flag[n]) return;
    __shared__ uint32_t h[4][HSIZE];
    const int t = threadIdx.x;
    for (int i = t; i < 4 * HSIZE; i += 256) (&h[0][0])[i] = 0u;
    __syncthreads();
    const int rem = blk % BPI, ch = rem / LBLK, lb = rem % LBLK;
    const int l0 = lb * LPB + t * 4;
    const float4 cr = *(const float4*)&ctr[(size_t)n * LL + l0];
    const float cv[4] = { sigm(cr.x), sigm(cr.y), sigm(cr.z), sigm(cr.w) };
    uint32_t* hw = h[t >> 6];
    const float* base = cls + ((size_t)n * CC + ch * CPCH) * LL + l0;
#pragma unroll 1
    for (int cc = 0; cc < CPCH; ++cc) {
        const float4 x = *(const float4*)&base[(size_t)cc * LL];
        const float pv[4] = { sigm(x.x), sigm(x.y), sigm(x.z), sigm(x.w) };
#pragma unroll
        for (int k = 0; k < 4; ++k)
            if (pv[k] > 0.05f)
                atomicAdd(&hw[__float_as_uint(pv[k] * cv[k]) >> 19], 1u);
    }
    __syncthreads();
    for (int b = t; b < HSIZE; b += 256) {
        const uint32_t s = h[0][b] + h[1][b] + h[2][b] + h[3][b];
        if (s) atomicAdd(&ghistC[n * HSIZE + b], s);
    }
}

__global__ __launch_bounds__(256) void k_fbthresh(const uint32_t* __restrict__ ghistC,
                                                  const uint32_t* __restrict__ flag,
                                                  uint32_t* __restrict__ thr2) {
    const int n = blockIdx.x;
    if (flag[n]) return;
    __shared__ uint32_t h[HSIZE];
    __shared__ uint32_t chunk[256];
    const int t = threadIdx.x;
    for (int b = t; b < HSIZE; b += 256) h[b] = ghistC[n * HSIZE + b];
    __syncthreads();
    uint32_t s = 0;
    for (int k = 0; k < 8; ++k) s += h[t * 8 + k];
    chunk[t] = s;
    __syncthreads();
    if (t == 0) {
        uint32_t cum = 0;
        int T = 0;
        for (int c = 255; c >= 0; --c) {
            if (cum + chunk[c] >= (uint32_t)PRE_K) {
                for (int b = c * 8 + 7; b >= c * 8; --b) {
                    cum += h[b];
                    if (cum >= (uint32_t)PRE_K) { T = b; break; }
                }
                break;
            }
            cum += chunk[c];
        }
        thr2[n] = ((uint32_t)T) << 19;
    }
}

__global__ __launch_bounds__(256) void k_fbcollect(const float* __restrict__ cls,
                                                   const float* __restrict__ ctr,
                                                   const uint32_t* __restrict__ flag,
                                                   const uint32_t* __restrict__ thr2,
                                                   uint32_t* __restrict__ cntFB,
                                                   u64* __restrict__ candFB) {
    const int blk = blockIdx.x;
    const int n = blk / BPI;
    if (flag[n]) return;
    const int t = threadIdx.x;
    const int rem = blk % BPI, ch = rem / LBLK, lb = rem % LBLK;
    const int l0 = lb * LPB + t * 4;
    const uint32_t th = thr2[n];
    const float4 cr = *(const float4*)&ctr[(size_t)n * LL + l0];
    const float cv[4] = { sigm(cr.x), sigm(cr.y), sigm(cr.z), sigm(cr.w) };
    const float* base = cls + ((size_t)n * CC + ch * CPCH) * LL + l0;
#pragma unroll 1
    for (int cc = 0; cc < CPCH; ++cc) {
        const float4 x = *(const float4*)&base[(size_t)cc * LL];
        const float pv[4] = { sigm(x.x), sigm(x.y), sigm(x.z), sigm(x.w) };
#pragma unroll
        for (int k = 0; k < 4; ++k) {
            if (pv[k] > 0.05f) {
                const uint32_t bits = __float_as_uint(pv[k] * cv[k]);
                if (bits >= th) {
                    uint32_t pos = atomicAdd(&cntFB[n], 1u);
                    if (pos < (uint32_t)CAPFB) {
                        uint32_t idx = (uint32_t)(l0 + k) * CC + (uint32_t)(ch * CPCH + cc);
                        candFB[(size_t)n * CAPFB + pos] =
                            ((u64)bits << 32) | (uint32_t)(~idx);
                    }
                }
            }
        }
    }
}

// ---------------------------------------------------------------------------
// K6: per image: gather >= thr2 into LDS, barrier-free O(M^2) rank-sort
// (keys unique -> exact, stable == JAX tie order), decode by rank into SoA.
__global__ __launch_bounds__(1024) void k_prep(const u64* __restrict__ candS,
                                               const uint32_t* __restrict__ listlen,
                                               const u64* __restrict__ candFB,
                                               const uint32_t* __restrict__ cntFB,
                                               const uint32_t* __restrict__ thr2,
                                               const uint32_t* __restrict__ flag,
                                               const float* __restrict__ reg,
                                               const float* __restrict__ anch,
                                               float* __restrict__ X1, float* __restrict__ Y1,
                                               float* __restrict__ X2, float* __restrict__ Y2,
                                               float* __restrict__ AR, float* __restrict__ SC,
                                               int* __restrict__ CL) {
    __shared__ u64 list[CAP2];          // 64 KB
    __shared__ uint32_t s_cnt;
    const int n = blockIdx.x, t = threadIdx.x;
    if (t == 0) s_cnt = 0;
    __syncthreads();
    const bool fp = (flag[n] != 0);
    const u64* src = fp ? (candS + (size_t)n * CAPS) : (candFB + (size_t)n * CAPFB);
    const uint32_t len = fp ? listlen[n] : min(cntFB[n], (uint32_t)CAPFB);
    const u64 Tkey = ((u64)thr2[n]) << 32;
    for (uint32_t gi = t; gi < len; gi += 1024) {
        const u64 key = src[gi];
        if (key >= Tkey) {
            uint32_t pos = atomicAdd(&s_cnt, 1u);
            if (pos < (uint32_t)CAP2) list[pos] = key;
        }
    }
    const int gb = n * 1024;
    for (int r = t; r < PRE_K; r += 1024) {       // defaults (ranks never filled)
        X1[gb+r]=0.f; Y1[gb+r]=0.f; X2[gb+r]=0.f; Y2[gb+r]=0.f;
        AR[gb+r]=0.f; SC[gb+r]=0.f; CL[gb+r]=0;
    }
    __syncthreads();
    const uint32_t M = min(s_cnt, (uint32_t)CAP2);
    for (uint32_t ci = t; ci < M; ci += 1024) {
        const u64 key = list[ci];
        uint32_t rank = 0;
        for (uint32_t j = 0; j < M; ++j) rank += (list[j] > key);   // LDS broadcast
        if (rank < (uint32_t)PRE_K) {
            const uint32_t bits = (uint32_t)(key >> 32);
            const uint32_t idx = ~(uint32_t)key;
            const int l = (int)(idx / (uint32_t)CC);
            const int c = (int)(idx % (uint32_t)CC);
            const float4 a = *(const float4*)&anch[l * 4];
            const float r0 = reg[((size_t)n*4+0)*LL + l];
            const float r1 = reg[((size_t)n*4+1)*LL + l];
            const float r2 = reg[((size_t)n*4+2)*LL + l];
            const float r3 = reg[((size_t)n*4+3)*LL + l];
            const float w  = a.z - a.x + 1.0f;
            const float h  = a.w - a.y + 1.0f;
            const float cx = a.x + 0.5f * w;
            const float cy = a.y + 0.5f * h;
            const float dx = r0 / 10.0f, dy = r1 / 10.0f;
            const float dw = fminf(r2 / 5.0f, CLIPV), dh = fminf(r3 / 5.0f, CLIPV);
            const float pcx = dx * w + cx, pcy = dy * h + cy;
            const float pw = expf(dw) * w, ph = expf(dh) * h;
            float x1 = pcx - 0.5f * (pw - 1.0f);
            float y1 = pcy - 0.5f * (ph - 1.0f);
            float x2 = pcx + 0.5f * (pw - 1.0f);
            float y2 = pcy + 0.5f * (ph - 1.0f);
            x1 = fminf(fmaxf(x1, 0.0f), IMGM1);
            y1 = fminf(fmaxf(y1, 0.0f), IMGM1);
            x2 = fminf(fmaxf(x2, 0.0f), IMGM1);
            y2 = fminf(fmaxf(y2, 0.0f), IMGM1);
            X1[gb+rank]=x1; Y1[gb+rank]=y1; X2[gb+rank]=x2; Y2[gb+rank]=y2;
            AR[gb+rank]=fmaxf(x2-x1,0.0f)*fmaxf(y2-y1,0.0f);
            SC[gb+rank]=sqrtf(__uint_as_float(bits));
            CL[gb+rank]=c+1;
        }
    }
}

// ---------------------------------------------------------------------------
// K7: parallel suppression bitmask. Block (n, tile): 64 rows x 16 words.
// Same-class IoU on unshifted boxes == reference's class-shifted IoU.
__global__ __launch_bounds__(256) void k_mask(const float* __restrict__ X1, const float* __restrict__ Y1,
                                              const float* __restrict__ X2, const float* __restrict__ Y2,
                                              const float* __restrict__ AR, const int* __restrict__ CL,
                                              u64* __restrict__ mask) {
    __shared__ float lx1[PRE_K], ly1[PRE_K], lx2[PRE_K], ly2[PRE_K], lar[PRE_K];
    __shared__ int lcl[PRE_K];
    const int n = blockIdx.x >> 4, tile = blockIdx.x & 15, t = threadIdx.x;
    const int gb = n * 1024;
    for (int i = t; i < PRE_K; i += 256) {
        lx1[i]=X1[gb+i]; ly1[i]=Y1[gb+i]; lx2[i]=X2[gb+i]; ly2[i]=Y2[gb+i];
        lar[i]=AR[gb+i]; lcl[i]=CL[gb+i];
    }
    __syncthreads();
#pragma unroll
    for (int u = 0; u < 4; ++u) {
        const int task = t + 256 * u;
        const int row = task >> 4, word = task & 15;
        const int gr = tile * 64 + row;
        u64 bits = 0ull;
        if (gr < PRE_K) {
            const int rcl = lcl[gr];
            if (rcl != 0) {
                const float rx1=lx1[gr], ry1=ly1[gr], rx2=lx2[gr], ry2=ly2[gr], rar=lar[gr];
                const int jb = word * 64;
                for (int jj = 0; jj < 64; ++jj) {
                    const int j = jb + jj;
                    if (j > gr && j < PRE_K && lcl[j] == rcl) {
                        const float xx1 = fmaxf(rx1, lx1[j]);
                        const float yy1 = fmaxf(ry1, ly1[j]);
                        const float xx2 = fminf(rx2, lx2[j]);
                        const float yy2 = fminf(ry2, ly2[j]);
                        const float iw = fmaxf(xx2 - xx1, 0.0f);
                        const float ih = fmaxf(yy2 - yy1, 0.0f);
                        const float inter = iw * ih;
                        const float iou = inter / (rar + lar[j] - inter + 1e-9f);
                        if (iou > NMS_T) bits |= (1ull << jj);
                    }
                }
            }
        }
        mask[((size_t)(gb + ((gr < 1024) ? gr : 0)) ) * 16 + word] = bits;   // gr<1024 always
    }
}

// ---------------------------------------------------------------------------
// K8: single-wave serial suppression scan (no barriers in the loop; early
// exit at 100 kept -- suppression only flows forward => exact) + output.
__global__ __launch_bounds__(256) void k_final(const u64* __restrict__ mask,
                                               const float* __restrict__ X1, const float* __restrict__ Y1,
                                               const float* __restrict__ X2, const float* __restrict__ Y2,
                                               const float* __restrict__ SC, const int* __restrict__ CL,
                                               float* __restrict__ out) {
    __shared__ u64 lmask[256 * 16];   // rows 0..255 cached (scan rarely passes ~130)
    __shared__ int lcl[PRE_K];
    __shared__ int s_keep[POST_K];
    __shared__ int s_kept;
    const int n = blockIdx.x, t = threadIdx.x;
    const int gb = n * 1024;
    for (int i = t; i < 256 * 16; i += 256) lmask[i] = mask[(size_t)gb * 16 + i];
    for (int i = t; i < PRE_K; i += 256) lcl[i] = CL[gb + i];
    __syncthreads();
    if (t < 64) {
        u64 sup = 0ull;                 // lane j<16 holds suppressed-bits word j
        int kept = 0;
        for (int i = 0; i < PRE_K; ++i) {
            const int w = i >> 6, b = i & 63;
            const unsigned int lo = __shfl((unsigned int)(sup & 0xffffffffu), w);
            const unsigned int hi = __shfl((unsigned int)(sup >> 32), w);
            const u64 supw = ((u64)hi << 32) | lo;
            const bool keep = (lcl[i] != 0) && !((supw >> b) & 1ull);
            if (keep) {
                if (t == 0) s_keep[kept] = i;
                ++kept;
                if (kept >= POST_K) break;
                if (t < 16) {
                    const u64 row = (i < 256) ? lmask[i * 16 + t]
                                              : mask[(size_t)(gb + i) * 16 + t];
                    sup |= row;
                }
            }
        }
        if (t == 0) s_kept = kept;
    }
    __syncthreads();
    if (t < POST_K) {
        float o0=0.f, o1=0.f, o2=0.f, o3=0.f, o4=0.f, lab=0.f;
        if (t < s_kept) {
            const int i = s_keep[t];
            o0=X1[gb+i]; o1=Y1[gb+i]; o2=X2[gb+i]; o3=Y2[gb+i];
            o4=SC[gb+i]; lab=(float)CL[gb+i];
        }
        float* dets = out + (size_t)(n * POST_K + t) * 5;
        dets[0]=o0; dets[1]=o1; dets[2]=o2; dets[3]=o3; dets[4]=o4;
        out[(size_t)NI * POST_K * 5 + (size_t)n * POST_K + t] = lab;
    }
}

// ---------------------------------------------------------------------------
extern "C" void kernel_launch(void* const* d_in, const int* in_sizes, int n_in,
                              void* d_out, int out_size, void* d_ws, size_t ws_size,
                              hipStream_t stream) {
    const float* reg  = (const float*)d_in[0];
    const float* ctr  = (const float*)d_in[1];
    const float* cls  = (const float*)d_in[2];
    const float* anch = (const float*)d_in[3];
    float* out = (float*)d_out;

    char* ws = (char*)d_ws;
    size_t off = 0;
    uint32_t* cntS   = (uint32_t*)(ws + off); off += 32;
    uint32_t* ovf    = (uint32_t*)(ws + off); off += 32;
    uint32_t* cntFB  = (uint32_t*)(ws + off); off += 32;
    uint32_t* ghistC = (uint32_t*)(ws + off); off += (size_t)NI * HSIZE * 4;  // 64 KB
    const size_t zbytes = off;                        // zero [cntS|ovf|cntFB|ghistC]
    uint32_t* thr2    = (uint32_t*)(ws + off); off += 32;
    uint32_t* listlen = (uint32_t*)(ws + off); off += 32;
    uint32_t* flg     = (uint32_t*)(ws + off); off += 32;
    u64* candS  = (u64*)(ws + off); off += (size_t)NI * CAPS * 8;   // 3 MB
    u64* candFB = (u64*)(ws + off); off += (size_t)NI * CAPFB * 8;  // 512 KB
    float* X1 = (float*)(ws + off); off += NI * 1024 * 4;
    float* Y1 = (float*)(ws + off); off += NI * 1024 * 4;
    float* X2 = (float*)(ws + off); off += NI * 1024 * 4;
    float* Y2 = (float*)(ws + off); off += NI * 1024 * 4;
    float* AR = (float*)(ws + off); off += NI * 1024 * 4;
    float* SC = (float*)(ws + off); off += NI * 1024 * 4;
    int*   CL = (int*)(ws + off);   off += NI * 1024 * 4;
    u64* mask = (u64*)(ws + off);   off += (size_t)NI * 1024 * 16 * 8;   // 1 MB

    hipMemsetAsync(cntS, 0, zbytes, stream);
    k_scan     <<<NI * BPI, 256, 0, stream>>>(cls, ctr, cntS, ovf, candS);
    k_thresh   <<<NI,       256, 0, stream>>>(candS, cntS, ovf, thr2, listlen, flg);
    k_fbhist   <<<NI * BPI, 256, 0, stream>>>(cls, ctr, flg, ghistC);
    k_fbthresh <<<NI,       256, 0, stream>>>(ghistC, flg, thr2);
    k_fbcollect<<<NI * BPI, 256, 0, stream>>>(cls, ctr, flg, thr2, cntFB, candFB);
    k_prep     <<<NI,      1024, 0, stream>>>(candS, listlen, candFB, cntFB, thr2, flg,
                                              reg, anch, X1, Y1, X2, Y2, AR, SC, CL);
    k_mask     <<<NI * 16,  256, 0, stream>>>(X1, Y1, X2, Y2, AR, CL, mask);
    k_final    <<<NI,       256, 0, stream>>>(mask, X1, Y1, X2, Y2, SC, CL, out);
}